// Round 1
// baseline (274.430 us; speedup 1.0000x reference)
//
#include <hip/hip_runtime.h>
#include <cstdint>
#include <cmath>

#define BB   2
#define NN   2048
#define DIMM 1024
#define NHH  16
#define DHH  64
#define MMR  (BB * NN)

typedef _Float16 half8  __attribute__((ext_vector_type(8)));
typedef _Float16 half4v __attribute__((ext_vector_type(4)));
typedef float    f32x4  __attribute__((ext_vector_type(4)));

#define GLD16(gp, lp)                                                          \
  __builtin_amdgcn_global_load_lds(                                            \
      (const __attribute__((address_space(1))) unsigned int*)(gp),             \
      (__attribute__((address_space(3))) unsigned int*)(lp), 16, 0, 0)

// ---------------- convert x (fp32 -> f16) ----------------
__global__ __launch_bounds__(256) void cvt_x_kernel(const float* __restrict__ x,
                                                    _Float16* __restrict__ xh) {
  int i = (blockIdx.x * 256 + threadIdx.x) * 4;
  float4 v = *(const float4*)(x + i);
  half4v h;
  h[0] = (_Float16)v.x; h[1] = (_Float16)v.y;
  h[2] = (_Float16)v.z; h[3] = (_Float16)v.w;
  *(half4v*)(xh + i) = h;
}

// ---------------- transpose + convert weights: W[k][n] -> Wt[n][k] f16 ----------------
__global__ __launch_bounds__(256) void transpose_w_kernel(
    const float* __restrict__ Wq, const float* __restrict__ Wk,
    const float* __restrict__ Wv, const float* __restrict__ Wo,
    _Float16* __restrict__ wt) {
  __shared__ float tile[64][65];
  int z = blockIdx.z;
  const float* W = (z == 0) ? Wq : (z == 1) ? Wk : (z == 2) ? Wv : Wo;
  _Float16* dst = wt + (size_t)z * 1024 * 1024;
  int r0 = blockIdx.x * 64;
  int c0 = blockIdx.y * 64;
  int t = threadIdx.x;
  int tr = t >> 4;
  int tc = (t & 15) * 4;
#pragma unroll
  for (int i = 0; i < 4; ++i) {
    float4 v = *(const float4*)(W + (size_t)(r0 + tr + i * 16) * 1024 + c0 + tc);
    tile[tr + i * 16][tc + 0] = v.x;
    tile[tr + i * 16][tc + 1] = v.y;
    tile[tr + i * 16][tc + 2] = v.z;
    tile[tr + i * 16][tc + 3] = v.w;
  }
  __syncthreads();
#pragma unroll
  for (int i = 0; i < 4; ++i) {
    int nl = tr + i * 16;
    half4v hv;
    hv[0] = (_Float16)tile[tc + 0][nl];
    hv[1] = (_Float16)tile[tc + 1][nl];
    hv[2] = (_Float16)tile[tc + 2][nl];
    hv[3] = (_Float16)tile[tc + 3][nl];
    *(half4v*)(dst + (size_t)(c0 + nl) * 1024 + r0 + tc) = hv;
  }
}

// ---------------- QKV GEMM: 128x128 tile, m97 structure ----------------
// 4 waves in 2x2, each wave owns a 64x64 sub-tile (acc[4][4]).
// K-step: 4x GLD16 DMA into XOR-swizzled [128][32] LDS, 8 ds_read_b128,
// 16 MFMA between 2 barriers (m97's verified ~900 TF histogram).
// Epilogue: two column-half rounds through Cs[128][65] f32 (unioned with
// staging LDS); each wave's 64-col span is exactly one head -> RoPE local.
__global__ __launch_bounds__(256) void gemm_qkv_kernel(
    const _Float16* __restrict__ xh, const _Float16* __restrict__ wt,
    float* __restrict__ ko, float* __restrict__ vo,
    _Float16* __restrict__ qh, _Float16* __restrict__ kh,
    _Float16* __restrict__ vth) {
  __shared__ __align__(16) char smem[128 * 65 * 4];
  _Float16* Ast = (_Float16*)smem;            // 128x32 f16 = 8 KB
  _Float16* Bst = (_Float16*)(smem + 8192);   // 8 KB
  float (*Cs)[65] = (float(*)[65])smem;       // 128x65 f32 (epilogue reuse)

  const int m0  = blockIdx.x * 128;
  const int mat = blockIdx.y >> 3;
  const int n0  = (blockIdx.y & 7) * 128;
  const _Float16* wb = wt + (size_t)mat * 1024 * 1024;
  const int t = threadIdx.x;
  const int wv = t >> 6, lane = t & 63, l16 = lane & 15, quad = lane >> 4;
  const int wr = wv >> 1, wc = wv & 1;
  // staging: thread t covers row r (and r+64), 16B chunk cl, XOR-swizzled
  const int r = t >> 2, cl = t & 3;
  const int c = cl ^ ((r >> 2) & 3);
  const _Float16* pa = xh + (size_t)(m0 + r) * 1024 + c * 8;
  const _Float16* pb = wb + (size_t)(n0 + r) * 1024 + c * 8;
  f32x4 acc[4][4] = {};
  int aoffs[4], boffs[4];
#pragma unroll
  for (int mi = 0; mi < 4; ++mi) {
    int arow = wr * 64 + mi * 16 + l16;
    aoffs[mi] = arow * 32 + (quad ^ ((arow >> 2) & 3)) * 8;
  }
#pragma unroll
  for (int n = 0; n < 4; ++n) {
    int brow = wc * 64 + n * 16 + l16;
    boffs[n] = brow * 32 + (quad ^ ((brow >> 2) & 3)) * 8;
  }
  for (int k0 = 0; k0 < 1024; k0 += 32) {
    __syncthreads();
    GLD16(pa + k0, Ast + wv * 512);
    GLD16(pa + 64 * 1024 + k0, Ast + 2048 + wv * 512);
    GLD16(pb + k0, Bst + wv * 512);
    GLD16(pb + 64 * 1024 + k0, Bst + 2048 + wv * 512);
    __syncthreads();
    half8 af[4], bf[4];
#pragma unroll
    for (int mi = 0; mi < 4; ++mi) af[mi] = *(const half8*)(Ast + aoffs[mi]);
#pragma unroll
    for (int n = 0; n < 4; ++n) bf[n] = *(const half8*)(Bst + boffs[n]);
#pragma unroll
    for (int mi = 0; mi < 4; ++mi)
#pragma unroll
      for (int n = 0; n < 4; ++n)
        acc[mi][n] = __builtin_amdgcn_mfma_f32_16x16x32_f16(af[mi], bf[n], acc[mi][n], 0, 0, 0);
  }
  // ---------- epilogue: 2 rounds over column halves (one head each) ----------
  const int lr = t >> 1;           // 0..127 (tile row)
  const int cseg = (t & 1) * 32;   // 0 or 32 within the 64-col head
  const int m = m0 + lr;
  const int b = m >> 11;
  const int pos = m & 2047;
  const float fpos = (float)pos;
  for (int ch = 0; ch < 2; ++ch) {
    __syncthreads();
    if (wc == ch) {
#pragma unroll
      for (int mi = 0; mi < 4; ++mi)
#pragma unroll
        for (int n = 0; n < 4; ++n)
#pragma unroll
          for (int rr = 0; rr < 4; ++rr)
            Cs[wr * 64 + mi * 16 + quad * 4 + rr][n * 16 + l16] = acc[mi][n][rr];
    }
    __syncthreads();
    const int h = (n0 >> 6) + ch;
    const int bhh = b * NHH + h;
    float vals[32];
    if (mat == 2) {
#pragma unroll
      for (int j = 0; j < 32; ++j) vals[j] = Cs[lr][cseg + j];
    } else {
      const bool lo = (cseg == 0);
#pragma unroll
      for (int j = 0; j < 32; ++j) {
        // jd == j for both halves -> invf constant-folds
        float invf = exp2f((float)j * -0.41524101186092029f);
        float ang = fpos * invf;
        float sv, cv;
        sincosf(ang, &sv, &cv);
        float partner = lo ? -Cs[lr][2 * j + 1] : Cs[lr][2 * j];
        vals[j] = Cs[lr][cseg + j] * cv + partner * sv;
      }
    }
    size_t rowb = ((size_t)bhh * NN + pos) * DHH + cseg;
    if (mat == 0) {
#pragma unroll
      for (int j8 = 0; j8 < 4; ++j8) {
        half8 hv;
#pragma unroll
        for (int j = 0; j < 8; ++j) hv[j] = (_Float16)(vals[j8 * 8 + j] * 0.125f);
        *(half8*)(qh + rowb + j8 * 8) = hv;
      }
    } else if (mat == 1) {
#pragma unroll
      for (int j4 = 0; j4 < 8; ++j4) {
        float4 o;
        o.x = vals[j4 * 4 + 0]; o.y = vals[j4 * 4 + 1];
        o.z = vals[j4 * 4 + 2]; o.w = vals[j4 * 4 + 3];
        *(float4*)(ko + rowb + j4 * 4) = o;
      }
#pragma unroll
      for (int j8 = 0; j8 < 4; ++j8) {
        half8 hv;
#pragma unroll
        for (int j = 0; j < 8; ++j) hv[j] = (_Float16)vals[j8 * 8 + j];
        *(half8*)(kh + rowb + j8 * 8) = hv;
      }
    } else {
#pragma unroll
      for (int j4 = 0; j4 < 8; ++j4) {
        float4 o;
        o.x = vals[j4 * 4 + 0]; o.y = vals[j4 * 4 + 1];
        o.z = vals[j4 * 4 + 2]; o.w = vals[j4 * 4 + 3];
        *(float4*)(vo + rowb + j4 * 4) = o;
      }
#pragma unroll
      for (int j = 0; j < 32; ++j)
        vth[((size_t)bhh * DHH + cseg + j) * NN + pos] = (_Float16)vals[j];
    }
  }
}

// ---------------- MFMA flash attention v3 (causal), f16 ----------------
__global__ __launch_bounds__(256, 2) void fattn_kernel(
    const _Float16* __restrict__ qh, const _Float16* __restrict__ kh,
    const _Float16* __restrict__ vth, _Float16* __restrict__ ah) {
  __shared__ __align__(16) _Float16 Kt[2][4096];
  __shared__ __align__(16) _Float16 Vt[2][4096];
  __shared__ __align__(16) _Float16 Pb[4][16][72];
  const int qb = 15 - (int)blockIdx.x;
  const int bh = blockIdx.y;
  const int t = threadIdx.x;
  const int wv = t >> 6, lane = t & 63, l16 = lane & 15, quad = lane >> 4;
  const int q0 = qb * 128;
  const _Float16* kg = kh + (size_t)bh * NN * DHH;
  const _Float16* vg = vth + (size_t)bh * DHH * NN;
  half8 qf[2][2];
#pragma unroll
  for (int qt2 = 0; qt2 < 2; ++qt2) {
    const _Float16* qp =
        qh + ((size_t)bh * NN + q0 + wv * 32 + qt2 * 16 + l16) * DHH + quad * 8;
    qf[qt2][0] = *(const half8*)qp;
    qf[qt2][1] = *(const half8*)(qp + 32);
  }
  half8 ones;
#pragma unroll
  for (int j = 0; j < 8; ++j) ones[j] = (_Float16)1.f;
  f32x4 o[2][4] = {};
  f32x4 ls[2] = {};
  const int ktmax = 2 * qb + 1;
#pragma unroll
  for (int iss = 0; iss < 2; ++iss) {
    int cid = iss * 256 + wv * 64 + lane;
    int row = cid >> 3;
    int c = (cid & 7) ^ (row & 7);
    GLD16(kg + (size_t)row * DHH + c * 8, &Kt[0][(iss * 256 + wv * 64) * 8]);
    GLD16(vg + (size_t)row * NN + c * 8, &Vt[0][(iss * 256 + wv * 64) * 8]);
  }
  int cur = 0;
  for (int kt = 0; kt <= ktmax; ++kt) {
    __syncthreads();
    if (kt < ktmax) {
      const _Float16* kn = kg + (size_t)(kt + 1) * 64 * DHH;
      const _Float16* vn = vg + (kt + 1) * 64;
      int nb = cur ^ 1;
#pragma unroll
      for (int iss = 0; iss < 2; ++iss) {
        int cid = iss * 256 + wv * 64 + lane;
        int row = cid >> 3;
        int c = (cid & 7) ^ (row & 7);
        GLD16(kn + (size_t)row * DHH + c * 8, &Kt[nb][(iss * 256 + wv * 64) * 8]);
        GLD16(vn + (size_t)row * NN + c * 8, &Vt[nb][(iss * 256 + wv * 64) * 8]);
      }
    }
    if (kt * 64 <= q0 + wv * 32 + 31) {
      half8 kf[4][2], vf[4][2];
      const _Float16* Kb = Kt[cur];
      const _Float16* Vb = Vt[cur];
#pragma unroll
      for (int nt = 0; nt < 4; ++nt) {
        int row = nt * 16 + l16;
        int r7 = row & 7;
        kf[nt][0] = *(const half8*)(Kb + row * 64 + ((quad ^ r7) * 8));
        kf[nt][1] = *(const half8*)(Kb + row * 64 + (((quad + 4) ^ r7) * 8));
        vf[nt][0] = *(const half8*)(Vb + row * 64 + ((quad ^ r7) * 8));
        vf[nt][1] = *(const half8*)(Vb + row * 64 + (((quad + 4) ^ r7) * 8));
      }
#pragma unroll
      for (int qt2 = 0; qt2 < 2; ++qt2) {
        int base = q0 + wv * 32 + qt2 * 16;
        if (kt * 64 <= base + 15) {
          f32x4 s4[4];
#pragma unroll
          for (int nt = 0; nt < 4; ++nt) {
            f32x4 z = {};
            z = __builtin_amdgcn_mfma_f32_16x16x32_f16(qf[qt2][0], kf[nt][0], z, 0, 0, 0);
            s4[nt] = __builtin_amdgcn_mfma_f32_16x16x32_f16(qf[qt2][1], kf[nt][1], z, 0, 0, 0);
          }
          if (kt * 64 + 63 > base) {
#pragma unroll
            for (int nt = 0; nt < 4; ++nt) {
              int key = kt * 64 + nt * 16 + l16;
#pragma unroll
              for (int r = 0; r < 4; ++r) {
                float p = (key > base + quad * 4 + r) ? 0.f : __expf(s4[nt][r]);
                Pb[wv][quad * 4 + r][nt * 16 + l16] = (_Float16)p;
              }
            }
          } else {
#pragma unroll
            for (int nt = 0; nt < 4; ++nt)
#pragma unroll
              for (int r = 0; r < 4; ++r)
                Pb[wv][quad * 4 + r][nt * 16 + l16] = (_Float16)__expf(s4[nt][r]);
          }
          asm volatile("s_waitcnt lgkmcnt(0)" ::: "memory");
          half8 pf0 = *(const half8*)&Pb[wv][l16][quad * 8];
          half8 pf1 = *(const half8*)&Pb[wv][l16][32 + quad * 8];
#pragma unroll
          for (int nt = 0; nt < 4; ++nt) {
            o[qt2][nt] = __builtin_amdgcn_mfma_f32_16x16x32_f16(pf0, vf[nt][0], o[qt2][nt], 0, 0, 0);
            o[qt2][nt] = __builtin_amdgcn_mfma_f32_16x16x32_f16(pf1, vf[nt][1], o[qt2][nt], 0, 0, 0);
          }
          ls[qt2] = __builtin_amdgcn_mfma_f32_16x16x32_f16(pf0, ones, ls[qt2], 0, 0, 0);
          ls[qt2] = __builtin_amdgcn_mfma_f32_16x16x32_f16(pf1, ones, ls[qt2], 0, 0, 0);
        }
      }
    }
    cur ^= 1;
  }
  const int b = bh >> 4, h = bh & 15;
#pragma unroll
  for (int qt2 = 0; qt2 < 2; ++qt2)
#pragma unroll
    for (int r = 0; r < 4; ++r) {
      float inv = 1.f / ls[qt2][r];
      int pos = q0 + wv * 32 + qt2 * 16 + quad * 4 + r;
      size_t ob = ((size_t)(b * NN + pos)) * DIMM + h * DHH;
#pragma unroll
      for (int nt = 0; nt < 4; ++nt)
        ah[ob + nt * 16 + l16] = (_Float16)(o[qt2][nt][r] * inv);
    }
}

// ---------------- out GEMM: 128x128 tile, m97 structure + bias ----------------
__global__ __launch_bounds__(256) void gemm_out_kernel(
    const _Float16* __restrict__ ah, const _Float16* __restrict__ wot,
    const float* __restrict__ bo, float* __restrict__ out) {
  __shared__ __align__(16) _Float16 Ast[128 * 32];
  __shared__ __align__(16) _Float16 Bst[128 * 32];
  const int m0 = blockIdx.x * 128;
  const int n0 = blockIdx.y * 128;
  const int t = threadIdx.x;
  const int wv = t >> 6, lane = t & 63, l16 = lane & 15, quad = lane >> 4;
  const int wr = wv >> 1, wc = wv & 1;
  const int r = t >> 2, cl = t & 3;
  const int c = cl ^ ((r >> 2) & 3);
  const _Float16* pa = ah + (size_t)(m0 + r) * 1024 + c * 8;
  const _Float16* pb = wot + (size_t)(n0 + r) * 1024 + c * 8;
  f32x4 acc[4][4] = {};
  int aoffs[4], boffs[4];
#pragma unroll
  for (int mi = 0; mi < 4; ++mi) {
    int arow = wr * 64 + mi * 16 + l16;
    aoffs[mi] = arow * 32 + (quad ^ ((arow >> 2) & 3)) * 8;
  }
#pragma unroll
  for (int n = 0; n < 4; ++n) {
    int brow = wc * 64 + n * 16 + l16;
    boffs[n] = brow * 32 + (quad ^ ((brow >> 2) & 3)) * 8;
  }
  for (int k0 = 0; k0 < 1024; k0 += 32) {
    __syncthreads();
    GLD16(pa + k0, Ast + wv * 512);
    GLD16(pa + 64 * 1024 + k0, Ast + 2048 + wv * 512);
    GLD16(pb + k0, Bst + wv * 512);
    GLD16(pb + 64 * 1024 + k0, Bst + 2048 + wv * 512);
    __syncthreads();
    half8 af[4], bf[4];
#pragma unroll
    for (int mi = 0; mi < 4; ++mi) af[mi] = *(const half8*)(Ast + aoffs[mi]);
#pragma unroll
    for (int n = 0; n < 4; ++n) bf[n] = *(const half8*)(Bst + boffs[n]);
#pragma unroll
    for (int mi = 0; mi < 4; ++mi)
#pragma unroll
      for (int n = 0; n < 4; ++n)
        acc[mi][n] = __builtin_amdgcn_mfma_f32_16x16x32_f16(af[mi], bf[n], acc[mi][n], 0, 0, 0);
  }
#pragma unroll
  for (int mi = 0; mi < 4; ++mi)
#pragma unroll
    for (int n = 0; n < 4; ++n) {
      int col = n0 + wc * 64 + n * 16 + l16;
      float bias = bo[col];
#pragma unroll
      for (int rr = 0; rr < 4; ++rr)
        out[(size_t)(m0 + wr * 64 + mi * 16 + quad * 4 + rr) * 1024 + col] =
            acc[mi][n][rr] + bias;
    }
}

extern "C" void kernel_launch(void* const* d_in, const int* in_sizes, int n_in,
                              void* d_out, int out_size, void* d_ws, size_t ws_size,
                              hipStream_t stream) {
  (void)in_sizes; (void)n_in; (void)out_size; (void)ws_size;
  const float* x  = (const float*)d_in[0];
  const float* Wq = (const float*)d_in[1];
  const float* Wk = (const float*)d_in[2];
  const float* Wv = (const float*)d_in[3];
  const float* Wo = (const float*)d_in[4];
  const float* bo = (const float*)d_in[5];

  float* out = (float*)d_out;
  float* ko  = out + (size_t)MMR * DIMM;
  float* vo  = ko + (size_t)BB * NHH * NN * DHH;

  char* w = (char*)d_ws;
  _Float16* xh  = (_Float16*)w;                   // 8 MB (dead after gemm_qkv)
  _Float16* ah  = (_Float16*)w;                   // 8 MB (reuses xh region)
  _Float16* wt  = (_Float16*)(w + (8u << 20));    // 8 MB
  _Float16* qh  = (_Float16*)(w + (16u << 20));   // 8 MB (b,h,n,dh) roped, *0.125
  _Float16* kh  = (_Float16*)(w + (24u << 20));   // 8 MB (b,h,n,dh) roped
  _Float16* vth = (_Float16*)(w + (32u << 20));   // 8 MB (b,h,dh,n)

  hipLaunchKernelGGL(cvt_x_kernel, dim3(4096), dim3(256), 0, stream, x, xh);
  hipLaunchKernelGGL(transpose_w_kernel, dim3(16, 16, 4), dim3(256), 0, stream,
                     Wq, Wk, Wv, Wo, wt);
  hipLaunchKernelGGL(gemm_qkv_kernel, dim3(32, 24), dim3(256), 0, stream,
                     xh, wt, ko, vo, qh, kh, vth);
  hipLaunchKernelGGL(fattn_kernel, dim3(16, 32), dim3(256), 0, stream,
                     qh, kh, vth, ah);
  hipLaunchKernelGGL(gemm_out_kernel, dim3(32, 8), dim3(256), 0, stream,
                     ah, wt + (size_t)3 * 1024 * 1024, bo, out);
}

// Round 3
// 211.149 us; speedup vs baseline: 1.2997x; 1.2997x over previous
//
#include <hip/hip_runtime.h>
#include <cstdint>
#include <cmath>

#define BB   2
#define NN   2048
#define DIMM 1024
#define NHH  16
#define DHH  64
#define MMR  (BB * NN)

typedef _Float16 half8  __attribute__((ext_vector_type(8)));
typedef _Float16 half4v __attribute__((ext_vector_type(4)));
typedef float    f32x4  __attribute__((ext_vector_type(4)));

#define GLD16(gp, lp)                                                          \
  __builtin_amdgcn_global_load_lds(                                            \
      (const __attribute__((address_space(1))) unsigned int*)(gp),             \
      (__attribute__((address_space(3))) unsigned int*)(lp), 16, 0, 0)

// ---------------- convert x (fp32 -> f16) ----------------
__global__ __launch_bounds__(256) void cvt_x_kernel(const float* __restrict__ x,
                                                    _Float16* __restrict__ xh) {
  int i = (blockIdx.x * 256 + threadIdx.x) * 4;
  float4 v = *(const float4*)(x + i);
  half4v h;
  h[0] = (_Float16)v.x; h[1] = (_Float16)v.y;
  h[2] = (_Float16)v.z; h[3] = (_Float16)v.w;
  *(half4v*)(xh + i) = h;
}

// ---------------- transpose + convert weights: W[k][n] -> Wt[n][k] f16 ----------------
__global__ __launch_bounds__(256) void transpose_w_kernel(
    const float* __restrict__ Wq, const float* __restrict__ Wk,
    const float* __restrict__ Wv, const float* __restrict__ Wo,
    _Float16* __restrict__ wt) {
  __shared__ float tile[64][65];
  int z = blockIdx.z;
  const float* W = (z == 0) ? Wq : (z == 1) ? Wk : (z == 2) ? Wv : Wo;
  _Float16* dst = wt + (size_t)z * 1024 * 1024;
  int r0 = blockIdx.x * 64;
  int c0 = blockIdx.y * 64;
  int t = threadIdx.x;
  int tr = t >> 4;
  int tc = (t & 15) * 4;
#pragma unroll
  for (int i = 0; i < 4; ++i) {
    float4 v = *(const float4*)(W + (size_t)(r0 + tr + i * 16) * 1024 + c0 + tc);
    tile[tr + i * 16][tc + 0] = v.x;
    tile[tr + i * 16][tc + 1] = v.y;
    tile[tr + i * 16][tc + 2] = v.z;
    tile[tr + i * 16][tc + 3] = v.w;
  }
  __syncthreads();
#pragma unroll
  for (int i = 0; i < 4; ++i) {
    int nl = tr + i * 16;
    half4v hv;
    hv[0] = (_Float16)tile[tc + 0][nl];
    hv[1] = (_Float16)tile[tc + 1][nl];
    hv[2] = (_Float16)tile[tc + 2][nl];
    hv[3] = (_Float16)tile[tc + 3][nl];
    *(half4v*)(dst + (size_t)(c0 + nl) * 1024 + r0 + tc) = hv;
  }
}

// ---------------- QKV GEMM: 64x64 tile, BK=64, dbuf + counted vmcnt ----------------
// Per K-step: issue next-tile GLD16s, vmcnt(4) (current tile drained, 4
// prefetches stay in flight ACROSS both raw barriers), s_barrier, ds_read +
// 8 MFMA, lgkmcnt(0) [reads must RETIRE before crossing: next iter's prefetch
// overwrites this buffer -- raw s_barrier does not drain lgkm], s_barrier.
// No vmcnt(0) in the main loop. Epilogue: R6's traffic-optimal RoPE/scatter.
__global__ __launch_bounds__(256) void gemm_qkv_kernel(
    const _Float16* __restrict__ xh, const _Float16* __restrict__ wt,
    float* __restrict__ ko, float* __restrict__ vo,
    _Float16* __restrict__ qh, _Float16* __restrict__ kh,
    _Float16* __restrict__ vth) {
  __shared__ __align__(16) char smem[32768];
  _Float16* As = (_Float16*)smem;            // [2][64][64] halfs, 16KB
  _Float16* Bs = (_Float16*)(smem + 16384);  // [2][64][64] halfs, 16KB
  float (*Cs)[65] = (float(*)[65])smem;      // 64x65 f32 epilogue reuse (16.6KB)

  const int m0  = blockIdx.x * 64;
  const int ngl = blockIdx.y * 64;
  const int mat = ngl >> 10;
  const int n0  = ngl & 1023;
  const _Float16* wb = wt + (size_t)mat * 1024 * 1024;
  const int t = threadIdx.x;
  const int wv = t >> 6, lane = t & 63, l16 = lane & 15, quad = lane >> 4;
  // staging: thread t covers rows r and r+32, 16B chunk cl, XOR-swizzled by row
  const int r  = t >> 3;       // 0..31
  const int cl = t & 7;
  const int csw = (cl ^ (r & 7)) * 8;   // (r+32)&7 == r&7
  const _Float16* pa0 = xh + (size_t)(m0 + r) * 1024 + csw;
  const _Float16* pa1 = pa0 + 32 * 1024;
  const _Float16* pb0 = wb + (size_t)(n0 + r) * 1024 + csw;
  const _Float16* pb1 = pb0 + 32 * 1024;
  f32x4 acc[4] = {};
  const int arow = wv * 16 + l16;
  const int a7 = arow & 7;
  // prologue: stage buffer 0 (k0 = 0)
  GLD16(pa0, As + wv * 512);
  GLD16(pa1, As + 2048 + wv * 512);
  GLD16(pb0, Bs + wv * 512);
  GLD16(pb1, Bs + 2048 + wv * 512);
  int cur = 0;
  for (int k0 = 0; k0 < 1024; k0 += 64) {
    if (k0 + 64 < 1024) {
      const int nb = cur ^ 1;
      GLD16(pa0 + k0 + 64, As + nb * 4096 + wv * 512);
      GLD16(pa1 + k0 + 64, As + nb * 4096 + 2048 + wv * 512);
      GLD16(pb0 + k0 + 64, Bs + nb * 4096 + wv * 512);
      GLD16(pb1 + k0 + 64, Bs + nb * 4096 + 2048 + wv * 512);
      asm volatile("s_waitcnt vmcnt(4)" ::: "memory");
    } else {
      asm volatile("s_waitcnt vmcnt(0)" ::: "memory");
    }
    __builtin_amdgcn_s_barrier();
    asm volatile("" ::: "memory");
    const _Float16* Ab = As + cur * 4096;
    const _Float16* Bb = Bs + cur * 4096;
    half8 af0 = *(const half8*)(Ab + arow * 64 + (quad ^ a7) * 8);
    half8 af1 = *(const half8*)(Ab + arow * 64 + ((4 + quad) ^ a7) * 8);
#pragma unroll
    for (int nt = 0; nt < 4; ++nt) {
      int brow = nt * 16 + l16;
      int b7 = brow & 7;
      half8 bf0 = *(const half8*)(Bb + brow * 64 + (quad ^ b7) * 8);
      half8 bf1 = *(const half8*)(Bb + brow * 64 + ((4 + quad) ^ b7) * 8);
      acc[nt] = __builtin_amdgcn_mfma_f32_16x16x32_f16(af0, bf0, acc[nt], 0, 0, 0);
      acc[nt] = __builtin_amdgcn_mfma_f32_16x16x32_f16(af1, bf1, acc[nt], 0, 0, 0);
    }
    // reads of buf[cur] must be complete (not just issued) before any wave
    // crosses this barrier and overwrites buf[cur] with the next prefetch.
    asm volatile("s_waitcnt lgkmcnt(0)" ::: "memory");
    __builtin_amdgcn_s_barrier();
    asm volatile("" ::: "memory");
    cur ^= 1;
  }
  // ---------- epilogue (R6 verbatim): Cs reuses smem, safe after final barrier ----------
#pragma unroll
  for (int nt = 0; nt < 4; ++nt)
#pragma unroll
    for (int rr = 0; rr < 4; ++rr)
      Cs[wv * 16 + quad * 4 + rr][nt * 16 + l16] = acc[nt][rr];
  __syncthreads();
  int lr = t >> 2;
  int cseg = (t & 3) * 16;
  int m = m0 + lr;
  int b = m >> 11;
  int pos = m & 2047;
  int h = n0 >> 6;
  int bhh = b * NHH + h;
  float vals[16];
  if (mat == 2) {
#pragma unroll
    for (int j = 0; j < 16; ++j) vals[j] = Cs[lr][cseg + j];
  } else {
    float fpos = (float)pos;
#pragma unroll
    for (int j = 0; j < 16; ++j) {
      int i = cseg + j;
      int jd = (i < 32) ? i : (i - 32);
      float invf = exp2f((float)jd * -0.41524101186092029f);
      float ang = fpos * invf;
      float sv, cv;
      sincosf(ang, &sv, &cv);
      float partner = (i < 32) ? -Cs[lr][2 * i + 1] : Cs[lr][2 * (i - 32)];
      vals[j] = Cs[lr][i] * cv + partner * sv;
    }
  }
  size_t rowb = ((size_t)bhh * NN + pos) * DHH + cseg;
  if (mat == 0) {
    half8 h0, h1;
#pragma unroll
    for (int j = 0; j < 8; ++j) { h0[j] = (_Float16)(vals[j] * 0.125f); h1[j] = (_Float16)(vals[8 + j] * 0.125f); }
    *(half8*)(qh + rowb) = h0;
    *(half8*)(qh + rowb + 8) = h1;
  } else if (mat == 1) {
#pragma unroll
    for (int j4 = 0; j4 < 4; ++j4) {
      float4 o;
      o.x = vals[j4 * 4 + 0]; o.y = vals[j4 * 4 + 1];
      o.z = vals[j4 * 4 + 2]; o.w = vals[j4 * 4 + 3];
      *(float4*)(ko + rowb + j4 * 4) = o;
    }
    half8 h0, h1;
#pragma unroll
    for (int j = 0; j < 8; ++j) { h0[j] = (_Float16)vals[j]; h1[j] = (_Float16)vals[8 + j]; }
    *(half8*)(kh + rowb) = h0;
    *(half8*)(kh + rowb + 8) = h1;
  } else {
#pragma unroll
    for (int j4 = 0; j4 < 4; ++j4) {
      float4 o;
      o.x = vals[j4 * 4 + 0]; o.y = vals[j4 * 4 + 1];
      o.z = vals[j4 * 4 + 2]; o.w = vals[j4 * 4 + 3];
      *(float4*)(vo + rowb + j4 * 4) = o;
    }
#pragma unroll
    for (int j = 0; j < 16; ++j)
      vth[((size_t)bhh * DHH + cseg + j) * NN + pos] = (_Float16)vals[j];
  }
}

// ---------------- MFMA flash attention v3 (causal), f16 ----------------
__global__ __launch_bounds__(256, 2) void fattn_kernel(
    const _Float16* __restrict__ qh, const _Float16* __restrict__ kh,
    const _Float16* __restrict__ vth, _Float16* __restrict__ ah) {
  __shared__ __align__(16) _Float16 Kt[2][4096];
  __shared__ __align__(16) _Float16 Vt[2][4096];
  __shared__ __align__(16) _Float16 Pb[4][16][72];
  const int qb = 15 - (int)blockIdx.x;
  const int bh = blockIdx.y;
  const int t = threadIdx.x;
  const int wv = t >> 6, lane = t & 63, l16 = lane & 15, quad = lane >> 4;
  const int q0 = qb * 128;
  const _Float16* kg = kh + (size_t)bh * NN * DHH;
  const _Float16* vg = vth + (size_t)bh * DHH * NN;
  half8 qf[2][2];
#pragma unroll
  for (int qt2 = 0; qt2 < 2; ++qt2) {
    const _Float16* qp =
        qh + ((size_t)bh * NN + q0 + wv * 32 + qt2 * 16 + l16) * DHH + quad * 8;
    qf[qt2][0] = *(const half8*)qp;
    qf[qt2][1] = *(const half8*)(qp + 32);
  }
  half8 ones;
#pragma unroll
  for (int j = 0; j < 8; ++j) ones[j] = (_Float16)1.f;
  f32x4 o[2][4] = {};
  f32x4 ls[2] = {};
  const int ktmax = 2 * qb + 1;
#pragma unroll
  for (int iss = 0; iss < 2; ++iss) {
    int cid = iss * 256 + wv * 64 + lane;
    int row = cid >> 3;
    int c = (cid & 7) ^ (row & 7);
    GLD16(kg + (size_t)row * DHH + c * 8, &Kt[0][(iss * 256 + wv * 64) * 8]);
    GLD16(vg + (size_t)row * NN + c * 8, &Vt[0][(iss * 256 + wv * 64) * 8]);
  }
  int cur = 0;
  for (int kt = 0; kt <= ktmax; ++kt) {
    __syncthreads();
    if (kt < ktmax) {
      const _Float16* kn = kg + (size_t)(kt + 1) * 64 * DHH;
      const _Float16* vn = vg + (kt + 1) * 64;
      int nb = cur ^ 1;
#pragma unroll
      for (int iss = 0; iss < 2; ++iss) {
        int cid = iss * 256 + wv * 64 + lane;
        int row = cid >> 3;
        int c = (cid & 7) ^ (row & 7);
        GLD16(kn + (size_t)row * DHH + c * 8, &Kt[nb][(iss * 256 + wv * 64) * 8]);
        GLD16(vn + (size_t)row * NN + c * 8, &Vt[nb][(iss * 256 + wv * 64) * 8]);
      }
    }
    if (kt * 64 <= q0 + wv * 32 + 31) {
      half8 kf[4][2], vf[4][2];
      const _Float16* Kb = Kt[cur];
      const _Float16* Vb = Vt[cur];
#pragma unroll
      for (int nt = 0; nt < 4; ++nt) {
        int row = nt * 16 + l16;
        int r7 = row & 7;
        kf[nt][0] = *(const half8*)(Kb + row * 64 + ((quad ^ r7) * 8));
        kf[nt][1] = *(const half8*)(Kb + row * 64 + (((quad + 4) ^ r7) * 8));
        vf[nt][0] = *(const half8*)(Vb + row * 64 + ((quad ^ r7) * 8));
        vf[nt][1] = *(const half8*)(Vb + row * 64 + (((quad + 4) ^ r7) * 8));
      }
#pragma unroll
      for (int qt2 = 0; qt2 < 2; ++qt2) {
        int base = q0 + wv * 32 + qt2 * 16;
        if (kt * 64 <= base + 15) {
          f32x4 s4[4];
#pragma unroll
          for (int nt = 0; nt < 4; ++nt) {
            f32x4 z = {};
            z = __builtin_amdgcn_mfma_f32_16x16x32_f16(qf[qt2][0], kf[nt][0], z, 0, 0, 0);
            s4[nt] = __builtin_amdgcn_mfma_f32_16x16x32_f16(qf[qt2][1], kf[nt][1], z, 0, 0, 0);
          }
          if (kt * 64 + 63 > base) {
#pragma unroll
            for (int nt = 0; nt < 4; ++nt) {
              int key = kt * 64 + nt * 16 + l16;
#pragma unroll
              for (int r = 0; r < 4; ++r) {
                float p = (key > base + quad * 4 + r) ? 0.f : __expf(s4[nt][r]);
                Pb[wv][quad * 4 + r][nt * 16 + l16] = (_Float16)p;
              }
            }
          } else {
#pragma unroll
            for (int nt = 0; nt < 4; ++nt)
#pragma unroll
              for (int r = 0; r < 4; ++r)
                Pb[wv][quad * 4 + r][nt * 16 + l16] = (_Float16)__expf(s4[nt][r]);
          }
          asm volatile("s_waitcnt lgkmcnt(0)" ::: "memory");
          half8 pf0 = *(const half8*)&Pb[wv][l16][quad * 8];
          half8 pf1 = *(const half8*)&Pb[wv][l16][32 + quad * 8];
#pragma unroll
          for (int nt = 0; nt < 4; ++nt) {
            o[qt2][nt] = __builtin_amdgcn_mfma_f32_16x16x32_f16(pf0, vf[nt][0], o[qt2][nt], 0, 0, 0);
            o[qt2][nt] = __builtin_amdgcn_mfma_f32_16x16x32_f16(pf1, vf[nt][1], o[qt2][nt], 0, 0, 0);
          }
          ls[qt2] = __builtin_amdgcn_mfma_f32_16x16x32_f16(pf0, ones, ls[qt2], 0, 0, 0);
          ls[qt2] = __builtin_amdgcn_mfma_f32_16x16x32_f16(pf1, ones, ls[qt2], 0, 0, 0);
        }
      }
    }
    cur ^= 1;
  }
  const int b = bh >> 4, h = bh & 15;
#pragma unroll
  for (int qt2 = 0; qt2 < 2; ++qt2)
#pragma unroll
    for (int r = 0; r < 4; ++r) {
      float inv = 1.f / ls[qt2][r];
      int pos = q0 + wv * 32 + qt2 * 16 + quad * 4 + r;
      size_t ob = ((size_t)(b * NN + pos)) * DIMM + h * DHH;
#pragma unroll
      for (int nt = 0; nt < 4; ++nt)
        ah[ob + nt * 16 + l16] = (_Float16)(o[qt2][nt][r] * inv);
    }
}

// ---------------- out GEMM: 64x64 tile, BK=64, dbuf + counted vmcnt + bias ----------------
__global__ __launch_bounds__(256) void gemm_out_kernel(
    const _Float16* __restrict__ ah, const _Float16* __restrict__ wot,
    const float* __restrict__ bo, float* __restrict__ out) {
  __shared__ __align__(16) char smem[32768];
  _Float16* As = (_Float16*)smem;
  _Float16* Bs = (_Float16*)(smem + 16384);
  const int m0 = blockIdx.x * 64;
  const int n0 = blockIdx.y * 64;
  const int t = threadIdx.x;
  const int wv = t >> 6, lane = t & 63, l16 = lane & 15, quad = lane >> 4;
  const int r  = t >> 3;
  const int cl = t & 7;
  const int csw = (cl ^ (r & 7)) * 8;
  const _Float16* pa0 = ah + (size_t)(m0 + r) * 1024 + csw;
  const _Float16* pa1 = pa0 + 32 * 1024;
  const _Float16* pb0 = wot + (size_t)(n0 + r) * 1024 + csw;
  const _Float16* pb1 = pb0 + 32 * 1024;
  f32x4 acc[4] = {};
  const int arow = wv * 16 + l16;
  const int a7 = arow & 7;
  GLD16(pa0, As + wv * 512);
  GLD16(pa1, As + 2048 + wv * 512);
  GLD16(pb0, Bs + wv * 512);
  GLD16(pb1, Bs + 2048 + wv * 512);
  int cur = 0;
  for (int k0 = 0; k0 < 1024; k0 += 64) {
    if (k0 + 64 < 1024) {
      const int nb = cur ^ 1;
      GLD16(pa0 + k0 + 64, As + nb * 4096 + wv * 512);
      GLD16(pa1 + k0 + 64, As + nb * 4096 + 2048 + wv * 512);
      GLD16(pb0 + k0 + 64, Bs + nb * 4096 + wv * 512);
      GLD16(pb1 + k0 + 64, Bs + nb * 4096 + 2048 + wv * 512);
      asm volatile("s_waitcnt vmcnt(4)" ::: "memory");
    } else {
      asm volatile("s_waitcnt vmcnt(0)" ::: "memory");
    }
    __builtin_amdgcn_s_barrier();
    asm volatile("" ::: "memory");
    const _Float16* Ab = As + cur * 4096;
    const _Float16* Bb = Bs + cur * 4096;
    half8 af0 = *(const half8*)(Ab + arow * 64 + (quad ^ a7) * 8);
    half8 af1 = *(const half8*)(Ab + arow * 64 + ((4 + quad) ^ a7) * 8);
#pragma unroll
    for (int nt = 0; nt < 4; ++nt) {
      int brow = nt * 16 + l16;
      int b7 = brow & 7;
      half8 bf0 = *(const half8*)(Bb + brow * 64 + (quad ^ b7) * 8);
      half8 bf1 = *(const half8*)(Bb + brow * 64 + ((4 + quad) ^ b7) * 8);
      acc[nt] = __builtin_amdgcn_mfma_f32_16x16x32_f16(af0, bf0, acc[nt], 0, 0, 0);
      acc[nt] = __builtin_amdgcn_mfma_f32_16x16x32_f16(af1, bf1, acc[nt], 0, 0, 0);
    }
    asm volatile("s_waitcnt lgkmcnt(0)" ::: "memory");
    __builtin_amdgcn_s_barrier();
    asm volatile("" ::: "memory");
    cur ^= 1;
  }
#pragma unroll
  for (int nt = 0; nt < 4; ++nt) {
    int col = n0 + nt * 16 + l16;
    float bias = bo[col];
#pragma unroll
    for (int rr = 0; rr < 4; ++rr) {
      out[(size_t)(m0 + wv * 16 + quad * 4 + rr) * 1024 + col] = acc[nt][rr] + bias;
    }
  }
}

extern "C" void kernel_launch(void* const* d_in, const int* in_sizes, int n_in,
                              void* d_out, int out_size, void* d_ws, size_t ws_size,
                              hipStream_t stream) {
  (void)in_sizes; (void)n_in; (void)out_size; (void)ws_size;
  const float* x  = (const float*)d_in[0];
  const float* Wq = (const float*)d_in[1];
  const float* Wk = (const float*)d_in[2];
  const float* Wv = (const float*)d_in[3];
  const float* Wo = (const float*)d_in[4];
  const float* bo = (const float*)d_in[5];

  float* out = (float*)d_out;
  float* ko  = out + (size_t)MMR * DIMM;
  float* vo  = ko + (size_t)BB * NHH * NN * DHH;

  char* w = (char*)d_ws;
  _Float16* xh  = (_Float16*)w;                   // 8 MB (dead after gemm_qkv)
  _Float16* ah  = (_Float16*)w;                   // 8 MB (reuses xh region)
  _Float16* wt  = (_Float16*)(w + (8u << 20));    // 8 MB
  _Float16* qh  = (_Float16*)(w + (16u << 20));   // 8 MB (b,h,n,dh) roped, *0.125
  _Float16* kh  = (_Float16*)(w + (24u << 20));   // 8 MB (b,h,n,dh) roped
  _Float16* vth = (_Float16*)(w + (32u << 20));   // 8 MB (b,h,dh,n)

  hipLaunchKernelGGL(cvt_x_kernel, dim3(4096), dim3(256), 0, stream, x, xh);
  hipLaunchKernelGGL(transpose_w_kernel, dim3(16, 16, 4), dim3(256), 0, stream,
                     Wq, Wk, Wv, Wo, wt);
  hipLaunchKernelGGL(gemm_qkv_kernel, dim3(64, 48), dim3(256), 0, stream,
                     xh, wt, ko, vo, qh, kh, vth);
  hipLaunchKernelGGL(fattn_kernel, dim3(16, 32), dim3(256), 0, stream,
                     qh, kh, vth, ah);
  hipLaunchKernelGGL(gemm_out_kernel, dim3(64, 16), dim3(256), 0, stream,
                     ah, wt + (size_t)3 * 1024 * 1024, bo, out);
}

// Round 4
// 210.196 us; speedup vs baseline: 1.3056x; 1.0045x over previous
//
#include <hip/hip_runtime.h>
#include <cstdint>
#include <cmath>

#define BB   2
#define NN   2048
#define DIMM 1024
#define NHH  16
#define DHH  64
#define MMR  (BB * NN)

typedef _Float16 half8  __attribute__((ext_vector_type(8)));
typedef _Float16 half4v __attribute__((ext_vector_type(4)));
typedef float    f32x4  __attribute__((ext_vector_type(4)));

#define GLD16(gp, lp)                                                          \
  __builtin_amdgcn_global_load_lds(                                            \
      (const __attribute__((address_space(1))) unsigned int*)(gp),             \
      (__attribute__((address_space(3))) unsigned int*)(lp), 16, 0, 0)

// ---------------- convert x (fp32 -> f16) ----------------
__global__ __launch_bounds__(256) void cvt_x_kernel(const float* __restrict__ x,
                                                    _Float16* __restrict__ xh) {
  int i = (blockIdx.x * 256 + threadIdx.x) * 4;
  float4 v = *(const float4*)(x + i);
  half4v h;
  h[0] = (_Float16)v.x; h[1] = (_Float16)v.y;
  h[2] = (_Float16)v.z; h[3] = (_Float16)v.w;
  *(half4v*)(xh + i) = h;
}

// ---------------- transpose + convert weights: W[k][n] -> Wt[n][k] f16 ----------------
__global__ __launch_bounds__(256) void transpose_w_kernel(
    const float* __restrict__ Wq, const float* __restrict__ Wk,
    const float* __restrict__ Wv, const float* __restrict__ Wo,
    _Float16* __restrict__ wt) {
  __shared__ float tile[64][65];
  int z = blockIdx.z;
  const float* W = (z == 0) ? Wq : (z == 1) ? Wk : (z == 2) ? Wv : Wo;
  _Float16* dst = wt + (size_t)z * 1024 * 1024;
  int r0 = blockIdx.x * 64;
  int c0 = blockIdx.y * 64;
  int t = threadIdx.x;
  int tr = t >> 4;
  int tc = (t & 15) * 4;
#pragma unroll
  for (int i = 0; i < 4; ++i) {
    float4 v = *(const float4*)(W + (size_t)(r0 + tr + i * 16) * 1024 + c0 + tc);
    tile[tr + i * 16][tc + 0] = v.x;
    tile[tr + i * 16][tc + 1] = v.y;
    tile[tr + i * 16][tc + 2] = v.z;
    tile[tr + i * 16][tc + 3] = v.w;
  }
  __syncthreads();
#pragma unroll
  for (int i = 0; i < 4; ++i) {
    int nl = tr + i * 16;
    half4v hv;
    hv[0] = (_Float16)tile[tc + 0][nl];
    hv[1] = (_Float16)tile[tc + 1][nl];
    hv[2] = (_Float16)tile[tc + 2][nl];
    hv[3] = (_Float16)tile[tc + 3][nl];
    *(half4v*)(dst + (size_t)(c0 + nl) * 1024 + r0 + tc) = hv;
  }
}

// ---------------- QKV GEMM: 64x64 tile, BK=64, dbuf + counted vmcnt ----------------
__global__ __launch_bounds__(256) void gemm_qkv_kernel(
    const _Float16* __restrict__ xh, const _Float16* __restrict__ wt,
    float* __restrict__ ko, float* __restrict__ vo,
    _Float16* __restrict__ qh, _Float16* __restrict__ kh,
    _Float16* __restrict__ vth) {
  __shared__ __align__(16) char smem[32768];
  _Float16* As = (_Float16*)smem;            // [2][64][64] halfs, 16KB
  _Float16* Bs = (_Float16*)(smem + 16384);  // [2][64][64] halfs, 16KB
  float (*Cs)[65] = (float(*)[65])smem;      // 64x65 f32 epilogue reuse (16.6KB)

  const int m0  = blockIdx.x * 64;
  const int ngl = blockIdx.y * 64;
  const int mat = ngl >> 10;
  const int n0  = ngl & 1023;
  const _Float16* wb = wt + (size_t)mat * 1024 * 1024;
  const int t = threadIdx.x;
  const int wv = t >> 6, lane = t & 63, l16 = lane & 15, quad = lane >> 4;
  const int r  = t >> 3;       // 0..31
  const int cl = t & 7;
  const int csw = (cl ^ (r & 7)) * 8;   // (r+32)&7 == r&7
  const _Float16* pa0 = xh + (size_t)(m0 + r) * 1024 + csw;
  const _Float16* pa1 = pa0 + 32 * 1024;
  const _Float16* pb0 = wb + (size_t)(n0 + r) * 1024 + csw;
  const _Float16* pb1 = pb0 + 32 * 1024;
  f32x4 acc[4] = {};
  const int arow = wv * 16 + l16;
  const int a7 = arow & 7;
  GLD16(pa0, As + wv * 512);
  GLD16(pa1, As + 2048 + wv * 512);
  GLD16(pb0, Bs + wv * 512);
  GLD16(pb1, Bs + 2048 + wv * 512);
  int cur = 0;
  for (int k0 = 0; k0 < 1024; k0 += 64) {
    if (k0 + 64 < 1024) {
      const int nb = cur ^ 1;
      GLD16(pa0 + k0 + 64, As + nb * 4096 + wv * 512);
      GLD16(pa1 + k0 + 64, As + nb * 4096 + 2048 + wv * 512);
      GLD16(pb0 + k0 + 64, Bs + nb * 4096 + wv * 512);
      GLD16(pb1 + k0 + 64, Bs + nb * 4096 + 2048 + wv * 512);
      asm volatile("s_waitcnt vmcnt(4)" ::: "memory");
    } else {
      asm volatile("s_waitcnt vmcnt(0)" ::: "memory");
    }
    __builtin_amdgcn_s_barrier();
    asm volatile("" ::: "memory");
    const _Float16* Ab = As + cur * 4096;
    const _Float16* Bb = Bs + cur * 4096;
    half8 af0 = *(const half8*)(Ab + arow * 64 + (quad ^ a7) * 8);
    half8 af1 = *(const half8*)(Ab + arow * 64 + ((4 + quad) ^ a7) * 8);
#pragma unroll
    for (int nt = 0; nt < 4; ++nt) {
      int brow = nt * 16 + l16;
      int b7 = brow & 7;
      half8 bf0 = *(const half8*)(Bb + brow * 64 + (quad ^ b7) * 8);
      half8 bf1 = *(const half8*)(Bb + brow * 64 + ((4 + quad) ^ b7) * 8);
      acc[nt] = __builtin_amdgcn_mfma_f32_16x16x32_f16(af0, bf0, acc[nt], 0, 0, 0);
      acc[nt] = __builtin_amdgcn_mfma_f32_16x16x32_f16(af1, bf1, acc[nt], 0, 0, 0);
    }
    asm volatile("s_waitcnt lgkmcnt(0)" ::: "memory");
    __builtin_amdgcn_s_barrier();
    asm volatile("" ::: "memory");
    cur ^= 1;
  }
  // ---------- epilogue: RoPE/scatter through Cs ----------
#pragma unroll
  for (int nt = 0; nt < 4; ++nt)
#pragma unroll
    for (int rr = 0; rr < 4; ++rr)
      Cs[wv * 16 + quad * 4 + rr][nt * 16 + l16] = acc[nt][rr];
  __syncthreads();
  int lr = t >> 2;
  int cseg = (t & 3) * 16;
  int m = m0 + lr;
  int b = m >> 11;
  int pos = m & 2047;
  int h = n0 >> 6;
  int bhh = b * NHH + h;
  float vals[16];
  if (mat == 2) {
#pragma unroll
    for (int j = 0; j < 16; ++j) vals[j] = Cs[lr][cseg + j];
  } else {
    float fpos = (float)pos;
#pragma unroll
    for (int j = 0; j < 16; ++j) {
      int i = cseg + j;
      int jd = (i < 32) ? i : (i - 32);
      float invf = exp2f((float)jd * -0.41524101186092029f);
      float ang = fpos * invf;
      float sv, cv;
      sincosf(ang, &sv, &cv);
      float partner = (i < 32) ? -Cs[lr][2 * i + 1] : Cs[lr][2 * (i - 32)];
      vals[j] = Cs[lr][i] * cv + partner * sv;
    }
  }
  size_t rowb = ((size_t)bhh * NN + pos) * DHH + cseg;
  if (mat == 0) {
    half8 h0, h1;
#pragma unroll
    for (int j = 0; j < 8; ++j) { h0[j] = (_Float16)(vals[j] * 0.125f); h1[j] = (_Float16)(vals[8 + j] * 0.125f); }
    *(half8*)(qh + rowb) = h0;
    *(half8*)(qh + rowb + 8) = h1;
  } else if (mat == 1) {
#pragma unroll
    for (int j4 = 0; j4 < 4; ++j4) {
      float4 o;
      o.x = vals[j4 * 4 + 0]; o.y = vals[j4 * 4 + 1];
      o.z = vals[j4 * 4 + 2]; o.w = vals[j4 * 4 + 3];
      *(float4*)(ko + rowb + j4 * 4) = o;
    }
    half8 h0, h1;
#pragma unroll
    for (int j = 0; j < 8; ++j) { h0[j] = (_Float16)vals[j]; h1[j] = (_Float16)vals[8 + j]; }
    *(half8*)(kh + rowb) = h0;
    *(half8*)(kh + rowb + 8) = h1;
  } else {
#pragma unroll
    for (int j4 = 0; j4 < 4; ++j4) {
      float4 o;
      o.x = vals[j4 * 4 + 0]; o.y = vals[j4 * 4 + 1];
      o.z = vals[j4 * 4 + 2]; o.w = vals[j4 * 4 + 3];
      *(float4*)(vo + rowb + j4 * 4) = o;
    }
#pragma unroll
    for (int j = 0; j < 16; ++j)
      vth[((size_t)bhh * DHH + cseg + j) * NN + pos] = (_Float16)vals[j];
  }
}

// ---------------- MFMA flash attention v4 (causal), f16 ----------------
// Changes vs v3: (1) 3-deep K/V pipeline with prefetch distance 2 and counted
// vmcnt(8) -- tiles kt+1, kt+2 stay in flight across the raw barriers, so each
// 16KB tile has ~2 compute periods of latency budget (v3's 1-deep + full
// syncthreads drain exposed HBM latency every iter: ~4300cy/iter measured).
// (2) XCD-chunked swizzle: all 16 q-blocks of one bh on one XCD -> K/V HBM-
// fetched once per bh, L2-hit afterwards (v3: FETCH 55MB, 1.7x duplication).
// Buffer hazard audit: buf consumed at iter kt is next written by iter kt+1's
// stage (tile kt+3 -> buf (cur+3)%3 == cur), gated by kt's lgkmcnt(0)+barrier.
__global__ __launch_bounds__(256, 2) void fattn_kernel(
    const _Float16* __restrict__ qh, const _Float16* __restrict__ kh,
    const _Float16* __restrict__ vth, _Float16* __restrict__ ah) {
  __shared__ __align__(16) _Float16 Kt[3][4096];
  __shared__ __align__(16) _Float16 Vt[3][4096];
  __shared__ __align__(16) _Float16 Pb[4][16][72];
  // XCD-chunked remap of the 512 linear block ids (HW: lin -> XCD lin&7).
  const int lin  = (int)blockIdx.x + 16 * (int)blockIdx.y;
  const int xcd  = lin & 7;
  const int slot = lin >> 3;                 // 0..63 within XCD
  const int qb   = 15 - (slot & 15);         // longest-first within each bh
  const int bh   = xcd * 4 + (slot >> 4);    // 4 bh per XCD
  const int t = threadIdx.x;
  const int wv = t >> 6, lane = t & 63, l16 = lane & 15, quad = lane >> 4;
  const int q0 = qb * 128;
  const _Float16* kg = kh + (size_t)bh * NN * DHH;
  const _Float16* vg = vth + (size_t)bh * DHH * NN;
  half8 qf[2][2];
#pragma unroll
  for (int qt2 = 0; qt2 < 2; ++qt2) {
    const _Float16* qp =
        qh + ((size_t)bh * NN + q0 + wv * 32 + qt2 * 16 + l16) * DHH + quad * 8;
    qf[qt2][0] = *(const half8*)qp;
    qf[qt2][1] = *(const half8*)(qp + 32);
  }
  half8 ones;
#pragma unroll
  for (int j = 0; j < 8; ++j) ones[j] = (_Float16)1.f;
  f32x4 o[2][4] = {};
  f32x4 ls[2] = {};
  const int ktmax = 2 * qb + 1;   // >= 1 always

#define STAGE_KV(tile, nb) do {                                                \
    const _Float16* kn_ = kg + (size_t)(tile) * 64 * DHH;                      \
    const _Float16* vn_ = vg + (tile) * 64;                                    \
    _Float16* kl_ = &Kt[nb][0];                                                \
    _Float16* vl_ = &Vt[nb][0];                                                \
    _Pragma("unroll")                                                          \
    for (int iss = 0; iss < 2; ++iss) {                                        \
      int cid = iss * 256 + wv * 64 + lane;                                    \
      int row = cid >> 3;                                                      \
      int c = (cid & 7) ^ (row & 7);                                           \
      GLD16(kn_ + (size_t)row * DHH + c * 8, kl_ + (iss * 256 + wv * 64) * 8); \
      GLD16(vn_ + (size_t)row * NN + c * 8, vl_ + (iss * 256 + wv * 64) * 8);  \
    }                                                                          \
  } while (0)

  // prologue: tiles 0 and 1 (ktmax >= 1 so both exist)
  STAGE_KV(0, 0);
  STAGE_KV(1, 1);
  int cur = 0;
  for (int kt = 0; kt <= ktmax; ++kt) {
    if (kt + 2 <= ktmax) {
      int nb = cur + 2; if (nb >= 3) nb -= 3;
      STAGE_KV(kt + 2, nb);
      asm volatile("s_waitcnt vmcnt(8)" ::: "memory");  // tile kt landed; kt+1,kt+2 in flight
    } else if (kt + 1 <= ktmax) {
      asm volatile("s_waitcnt vmcnt(4)" ::: "memory");
    } else {
      asm volatile("s_waitcnt vmcnt(0)" ::: "memory");
    }
    __builtin_amdgcn_s_barrier();
    asm volatile("" ::: "memory");
    if (kt * 64 <= q0 + wv * 32 + 31) {
      half8 kf[4][2], vf[4][2];
      const _Float16* Kb = &Kt[cur][0];
      const _Float16* Vb = &Vt[cur][0];
#pragma unroll
      for (int nt = 0; nt < 4; ++nt) {
        int row = nt * 16 + l16;
        int r7 = row & 7;
        kf[nt][0] = *(const half8*)(Kb + row * 64 + ((quad ^ r7) * 8));
        kf[nt][1] = *(const half8*)(Kb + row * 64 + (((quad + 4) ^ r7) * 8));
        vf[nt][0] = *(const half8*)(Vb + row * 64 + ((quad ^ r7) * 8));
        vf[nt][1] = *(const half8*)(Vb + row * 64 + (((quad + 4) ^ r7) * 8));
      }
#pragma unroll
      for (int qt2 = 0; qt2 < 2; ++qt2) {
        int base = q0 + wv * 32 + qt2 * 16;
        if (kt * 64 <= base + 15) {
          f32x4 s4[4];
#pragma unroll
          for (int nt = 0; nt < 4; ++nt) {
            f32x4 z = {};
            z = __builtin_amdgcn_mfma_f32_16x16x32_f16(qf[qt2][0], kf[nt][0], z, 0, 0, 0);
            s4[nt] = __builtin_amdgcn_mfma_f32_16x16x32_f16(qf[qt2][1], kf[nt][1], z, 0, 0, 0);
          }
          if (kt * 64 + 63 > base) {
#pragma unroll
            for (int nt = 0; nt < 4; ++nt) {
              int key = kt * 64 + nt * 16 + l16;
#pragma unroll
              for (int r = 0; r < 4; ++r) {
                float p = (key > base + quad * 4 + r) ? 0.f : __expf(s4[nt][r]);
                Pb[wv][quad * 4 + r][nt * 16 + l16] = (_Float16)p;
              }
            }
          } else {
#pragma unroll
            for (int nt = 0; nt < 4; ++nt)
#pragma unroll
              for (int r = 0; r < 4; ++r)
                Pb[wv][quad * 4 + r][nt * 16 + l16] = (_Float16)__expf(s4[nt][r]);
          }
          asm volatile("s_waitcnt lgkmcnt(0)" ::: "memory");
          half8 pf0 = *(const half8*)&Pb[wv][l16][quad * 8];
          half8 pf1 = *(const half8*)&Pb[wv][l16][32 + quad * 8];
#pragma unroll
          for (int nt = 0; nt < 4; ++nt) {
            o[qt2][nt] = __builtin_amdgcn_mfma_f32_16x16x32_f16(pf0, vf[nt][0], o[qt2][nt], 0, 0, 0);
            o[qt2][nt] = __builtin_amdgcn_mfma_f32_16x16x32_f16(pf1, vf[nt][1], o[qt2][nt], 0, 0, 0);
          }
          ls[qt2] = __builtin_amdgcn_mfma_f32_16x16x32_f16(pf0, ones, ls[qt2], 0, 0, 0);
          ls[qt2] = __builtin_amdgcn_mfma_f32_16x16x32_f16(pf1, ones, ls[qt2], 0, 0, 0);
        }
      }
    }
    // all LDS reads of buf[cur] must RETIRE before any wave crosses this
    // barrier: iter kt+1's stage writes tile kt+3 into this same buffer.
    asm volatile("s_waitcnt lgkmcnt(0)" ::: "memory");
    __builtin_amdgcn_s_barrier();
    asm volatile("" ::: "memory");
    cur = (cur == 2) ? 0 : cur + 1;
  }
#undef STAGE_KV
  const int b = bh >> 4, h = bh & 15;
#pragma unroll
  for (int qt2 = 0; qt2 < 2; ++qt2)
#pragma unroll
    for (int r = 0; r < 4; ++r) {
      float inv = 1.f / ls[qt2][r];
      int pos = q0 + wv * 32 + qt2 * 16 + quad * 4 + r;
      size_t ob = ((size_t)(b * NN + pos)) * DIMM + h * DHH;
#pragma unroll
      for (int nt = 0; nt < 4; ++nt)
        ah[ob + nt * 16 + l16] = (_Float16)(o[qt2][nt][r] * inv);
    }
}

// ---------------- out GEMM: 64x64 tile, BK=64, dbuf + counted vmcnt + bias ----------------
__global__ __launch_bounds__(256) void gemm_out_kernel(
    const _Float16* __restrict__ ah, const _Float16* __restrict__ wot,
    const float* __restrict__ bo, float* __restrict__ out) {
  __shared__ __align__(16) char smem[32768];
  _Float16* As = (_Float16*)smem;
  _Float16* Bs = (_Float16*)(smem + 16384);
  const int m0 = blockIdx.x * 64;
  const int n0 = blockIdx.y * 64;
  const int t = threadIdx.x;
  const int wv = t >> 6, lane = t & 63, l16 = lane & 15, quad = lane >> 4;
  const int r  = t >> 3;
  const int cl = t & 7;
  const int csw = (cl ^ (r & 7)) * 8;
  const _Float16* pa0 = ah + (size_t)(m0 + r) * 1024 + csw;
  const _Float16* pa1 = pa0 + 32 * 1024;
  const _Float16* pb0 = wot + (size_t)(n0 + r) * 1024 + csw;
  const _Float16* pb1 = pb0 + 32 * 1024;
  f32x4 acc[4] = {};
  const int arow = wv * 16 + l16;
  const int a7 = arow & 7;
  GLD16(pa0, As + wv * 512);
  GLD16(pa1, As + 2048 + wv * 512);
  GLD16(pb0, Bs + wv * 512);
  GLD16(pb1, Bs + 2048 + wv * 512);
  int cur = 0;
  for (int k0 = 0; k0 < 1024; k0 += 64) {
    if (k0 + 64 < 1024) {
      const int nb = cur ^ 1;
      GLD16(pa0 + k0 + 64, As + nb * 4096 + wv * 512);
      GLD16(pa1 + k0 + 64, As + nb * 4096 + 2048 + wv * 512);
      GLD16(pb0 + k0 + 64, Bs + nb * 4096 + wv * 512);
      GLD16(pb1 + k0 + 64, Bs + nb * 4096 + 2048 + wv * 512);
      asm volatile("s_waitcnt vmcnt(4)" ::: "memory");
    } else {
      asm volatile("s_waitcnt vmcnt(0)" ::: "memory");
    }
    __builtin_amdgcn_s_barrier();
    asm volatile("" ::: "memory");
    const _Float16* Ab = As + cur * 4096;
    const _Float16* Bb = Bs + cur * 4096;
    half8 af0 = *(const half8*)(Ab + arow * 64 + (quad ^ a7) * 8);
    half8 af1 = *(const half8*)(Ab + arow * 64 + ((4 + quad) ^ a7) * 8);
#pragma unroll
    for (int nt = 0; nt < 4; ++nt) {
      int brow = nt * 16 + l16;
      int b7 = brow & 7;
      half8 bf0 = *(const half8*)(Bb + brow * 64 + (quad ^ b7) * 8);
      half8 bf1 = *(const half8*)(Bb + brow * 64 + ((4 + quad) ^ b7) * 8);
      acc[nt] = __builtin_amdgcn_mfma_f32_16x16x32_f16(af0, bf0, acc[nt], 0, 0, 0);
      acc[nt] = __builtin_amdgcn_mfma_f32_16x16x32_f16(af1, bf1, acc[nt], 0, 0, 0);
    }
    asm volatile("s_waitcnt lgkmcnt(0)" ::: "memory");
    __builtin_amdgcn_s_barrier();
    asm volatile("" ::: "memory");
    cur ^= 1;
  }
#pragma unroll
  for (int nt = 0; nt < 4; ++nt) {
    int col = n0 + nt * 16 + l16;
    float bias = bo[col];
#pragma unroll
    for (int rr = 0; rr < 4; ++rr) {
      out[(size_t)(m0 + wv * 16 + quad * 4 + rr) * 1024 + col] = acc[nt][rr] + bias;
    }
  }
}

extern "C" void kernel_launch(void* const* d_in, const int* in_sizes, int n_in,
                              void* d_out, int out_size, void* d_ws, size_t ws_size,
                              hipStream_t stream) {
  (void)in_sizes; (void)n_in; (void)out_size; (void)ws_size;
  const float* x  = (const float*)d_in[0];
  const float* Wq = (const float*)d_in[1];
  const float* Wk = (const float*)d_in[2];
  const float* Wv = (const float*)d_in[3];
  const float* Wo = (const float*)d_in[4];
  const float* bo = (const float*)d_in[5];

  float* out = (float*)d_out;
  float* ko  = out + (size_t)MMR * DIMM;
  float* vo  = ko + (size_t)BB * NHH * NN * DHH;

  char* w = (char*)d_ws;
  _Float16* xh  = (_Float16*)w;                   // 8 MB (dead after gemm_qkv)
  _Float16* ah  = (_Float16*)w;                   // 8 MB (reuses xh region)
  _Float16* wt  = (_Float16*)(w + (8u << 20));    // 8 MB
  _Float16* qh  = (_Float16*)(w + (16u << 20));   // 8 MB (b,h,n,dh) roped, *0.125
  _Float16* kh  = (_Float16*)(w + (24u << 20));   // 8 MB (b,h,n,dh) roped
  _Float16* vth = (_Float16*)(w + (32u << 20));   // 8 MB (b,h,dh,n)

  hipLaunchKernelGGL(cvt_x_kernel, dim3(4096), dim3(256), 0, stream, x, xh);
  hipLaunchKernelGGL(transpose_w_kernel, dim3(16, 16, 4), dim3(256), 0, stream,
                     Wq, Wk, Wv, Wo, wt);
  hipLaunchKernelGGL(gemm_qkv_kernel, dim3(64, 48), dim3(256), 0, stream,
                     xh, wt, ko, vo, qh, kh, vth);
  hipLaunchKernelGGL(fattn_kernel, dim3(16, 32), dim3(256), 0, stream,
                     qh, kh, vth, ah);
  hipLaunchKernelGGL(gemm_out_kernel, dim3(64, 16), dim3(256), 0, stream,
                     ah, wt + (size_t)3 * 1024 * 1024, bo, out);
}

// Round 5
// 207.446 us; speedup vs baseline: 1.3229x; 1.0133x over previous
//
#include <hip/hip_runtime.h>
#include <cstdint>
#include <cmath>

#define BB   2
#define NN   2048
#define DIMM 1024
#define NHH  16
#define DHH  64
#define MMR  (BB * NN)

typedef _Float16 half8  __attribute__((ext_vector_type(8)));
typedef _Float16 half4v __attribute__((ext_vector_type(4)));
typedef float    f32x4  __attribute__((ext_vector_type(4)));

#define GLD16(gp, lp)                                                          \
  __builtin_amdgcn_global_load_lds(                                            \
      (const __attribute__((address_space(1))) unsigned int*)(gp),             \
      (__attribute__((address_space(3))) unsigned int*)(lp), 16, 0, 0)

// ---------------- convert x (fp32 -> f16) ----------------
__global__ __launch_bounds__(256) void cvt_x_kernel(const float* __restrict__ x,
                                                    _Float16* __restrict__ xh) {
  int i = (blockIdx.x * 256 + threadIdx.x) * 4;
  float4 v = *(const float4*)(x + i);
  half4v h;
  h[0] = (_Float16)v.x; h[1] = (_Float16)v.y;
  h[2] = (_Float16)v.z; h[3] = (_Float16)v.w;
  *(half4v*)(xh + i) = h;
}

// ---------------- transpose + convert weights: W[k][n] -> Wt[n][k] f16 ----------------
__global__ __launch_bounds__(256) void transpose_w_kernel(
    const float* __restrict__ Wq, const float* __restrict__ Wk,
    const float* __restrict__ Wv, const float* __restrict__ Wo,
    _Float16* __restrict__ wt) {
  __shared__ float tile[64][65];
  int z = blockIdx.z;
  const float* W = (z == 0) ? Wq : (z == 1) ? Wk : (z == 2) ? Wv : Wo;
  _Float16* dst = wt + (size_t)z * 1024 * 1024;
  int r0 = blockIdx.x * 64;
  int c0 = blockIdx.y * 64;
  int t = threadIdx.x;
  int tr = t >> 4;
  int tc = (t & 15) * 4;
#pragma unroll
  for (int i = 0; i < 4; ++i) {
    float4 v = *(const float4*)(W + (size_t)(r0 + tr + i * 16) * 1024 + c0 + tc);
    tile[tr + i * 16][tc + 0] = v.x;
    tile[tr + i * 16][tc + 1] = v.y;
    tile[tr + i * 16][tc + 2] = v.z;
    tile[tr + i * 16][tc + 3] = v.w;
  }
  __syncthreads();
#pragma unroll
  for (int i = 0; i < 4; ++i) {
    int nl = tr + i * 16;
    half4v hv;
    hv[0] = (_Float16)tile[tc + 0][nl];
    hv[1] = (_Float16)tile[tc + 1][nl];
    hv[2] = (_Float16)tile[tc + 2][nl];
    hv[3] = (_Float16)tile[tc + 3][nl];
    *(half4v*)(dst + (size_t)(c0 + nl) * 1024 + r0 + tc) = hv;
  }
}

// ---------------- QKV GEMM: 64x64 tile, BK=64, dbuf + counted vmcnt ----------------
__global__ __launch_bounds__(256) void gemm_qkv_kernel(
    const _Float16* __restrict__ xh, const _Float16* __restrict__ wt,
    float* __restrict__ ko, float* __restrict__ vo,
    _Float16* __restrict__ qh, _Float16* __restrict__ kh,
    _Float16* __restrict__ vth) {
  __shared__ __align__(16) char smem[32768];
  _Float16* As = (_Float16*)smem;            // [2][64][64] halfs, 16KB
  _Float16* Bs = (_Float16*)(smem + 16384);  // [2][64][64] halfs, 16KB
  float (*Cs)[65] = (float(*)[65])smem;      // 64x65 f32 epilogue reuse (16.6KB)

  const int m0  = blockIdx.x * 64;
  const int ngl = blockIdx.y * 64;
  const int mat = ngl >> 10;
  const int n0  = ngl & 1023;
  const _Float16* wb = wt + (size_t)mat * 1024 * 1024;
  const int t = threadIdx.x;
  const int wv = t >> 6, lane = t & 63, l16 = lane & 15, quad = lane >> 4;
  const int r  = t >> 3;       // 0..31
  const int cl = t & 7;
  const int csw = (cl ^ (r & 7)) * 8;   // (r+32)&7 == r&7
  const _Float16* pa0 = xh + (size_t)(m0 + r) * 1024 + csw;
  const _Float16* pa1 = pa0 + 32 * 1024;
  const _Float16* pb0 = wb + (size_t)(n0 + r) * 1024 + csw;
  const _Float16* pb1 = pb0 + 32 * 1024;
  f32x4 acc[4] = {};
  const int arow = wv * 16 + l16;
  const int a7 = arow & 7;
  GLD16(pa0, As + wv * 512);
  GLD16(pa1, As + 2048 + wv * 512);
  GLD16(pb0, Bs + wv * 512);
  GLD16(pb1, Bs + 2048 + wv * 512);
  int cur = 0;
  for (int k0 = 0; k0 < 1024; k0 += 64) {
    if (k0 + 64 < 1024) {
      const int nb = cur ^ 1;
      GLD16(pa0 + k0 + 64, As + nb * 4096 + wv * 512);
      GLD16(pa1 + k0 + 64, As + nb * 4096 + 2048 + wv * 512);
      GLD16(pb0 + k0 + 64, Bs + nb * 4096 + wv * 512);
      GLD16(pb1 + k0 + 64, Bs + nb * 4096 + 2048 + wv * 512);
      asm volatile("s_waitcnt vmcnt(4)" ::: "memory");
    } else {
      asm volatile("s_waitcnt vmcnt(0)" ::: "memory");
    }
    __builtin_amdgcn_s_barrier();
    asm volatile("" ::: "memory");
    const _Float16* Ab = As + cur * 4096;
    const _Float16* Bb = Bs + cur * 4096;
    half8 af0 = *(const half8*)(Ab + arow * 64 + (quad ^ a7) * 8);
    half8 af1 = *(const half8*)(Ab + arow * 64 + ((4 + quad) ^ a7) * 8);
#pragma unroll
    for (int nt = 0; nt < 4; ++nt) {
      int brow = nt * 16 + l16;
      int b7 = brow & 7;
      half8 bf0 = *(const half8*)(Bb + brow * 64 + (quad ^ b7) * 8);
      half8 bf1 = *(const half8*)(Bb + brow * 64 + ((4 + quad) ^ b7) * 8);
      acc[nt] = __builtin_amdgcn_mfma_f32_16x16x32_f16(af0, bf0, acc[nt], 0, 0, 0);
      acc[nt] = __builtin_amdgcn_mfma_f32_16x16x32_f16(af1, bf1, acc[nt], 0, 0, 0);
    }
    asm volatile("s_waitcnt lgkmcnt(0)" ::: "memory");
    __builtin_amdgcn_s_barrier();
    asm volatile("" ::: "memory");
    cur ^= 1;
  }
  // ---------- epilogue: RoPE/scatter through Cs ----------
#pragma unroll
  for (int nt = 0; nt < 4; ++nt)
#pragma unroll
    for (int rr = 0; rr < 4; ++rr)
      Cs[wv * 16 + quad * 4 + rr][nt * 16 + l16] = acc[nt][rr];
  __syncthreads();
  int lr = t >> 2;
  int cseg = (t & 3) * 16;
  int m = m0 + lr;
  int b = m >> 11;
  int pos = m & 2047;
  int h = n0 >> 6;
  int bhh = b * NHH + h;
  float vals[16];
  if (mat == 2) {
#pragma unroll
    for (int j = 0; j < 16; ++j) vals[j] = Cs[lr][cseg + j];
  } else {
    float fpos = (float)pos;
#pragma unroll
    for (int j = 0; j < 16; ++j) {
      int i = cseg + j;
      int jd = (i < 32) ? i : (i - 32);
      float invf = exp2f((float)jd * -0.41524101186092029f);
      float ang = fpos * invf;
      float sv, cv;
      sincosf(ang, &sv, &cv);
      float partner = (i < 32) ? -Cs[lr][2 * i + 1] : Cs[lr][2 * (i - 32)];
      vals[j] = Cs[lr][i] * cv + partner * sv;
    }
  }
  size_t rowb = ((size_t)bhh * NN + pos) * DHH + cseg;
  if (mat == 0) {
    half8 h0, h1;
#pragma unroll
    for (int j = 0; j < 8; ++j) { h0[j] = (_Float16)(vals[j] * 0.125f); h1[j] = (_Float16)(vals[8 + j] * 0.125f); }
    *(half8*)(qh + rowb) = h0;
    *(half8*)(qh + rowb + 8) = h1;
  } else if (mat == 1) {
#pragma unroll
    for (int j4 = 0; j4 < 4; ++j4) {
      float4 o;
      o.x = vals[j4 * 4 + 0]; o.y = vals[j4 * 4 + 1];
      o.z = vals[j4 * 4 + 2]; o.w = vals[j4 * 4 + 3];
      *(float4*)(ko + rowb + j4 * 4) = o;
    }
    half8 h0, h1;
#pragma unroll
    for (int j = 0; j < 8; ++j) { h0[j] = (_Float16)vals[j]; h1[j] = (_Float16)vals[8 + j]; }
    *(half8*)(kh + rowb) = h0;
    *(half8*)(kh + rowb + 8) = h1;
  } else {
#pragma unroll
    for (int j4 = 0; j4 < 4; ++j4) {
      float4 o;
      o.x = vals[j4 * 4 + 0]; o.y = vals[j4 * 4 + 1];
      o.z = vals[j4 * 4 + 2]; o.w = vals[j4 * 4 + 3];
      *(float4*)(vo + rowb + j4 * 4) = o;
    }
#pragma unroll
    for (int j = 0; j < 16; ++j)
      vth[((size_t)bhh * DHH + cseg + j) * NN + pos] = (_Float16)vals[j];
  }
}

// ---------------- MFMA flash attention v5 (causal), f16 ----------------
// v5: uniform-work pair-blocks. Each block sequentially processes q-tiles
// qb=15-p and qb=p for its (bh, p): (2(15-p)+2)+(2p+2) = 34 k-iters, exactly
// equal for every block. Grid 256 = 1 block/CU -> makespan is balanced by
// construction, no assumption on which blocks share a CU (v4's imbalance:
// co-resident same-qb pairs gave a 64-iter critical path vs 34 avg).
// XCD-chunked bh locality kept (4 bh/XCD, K/V 2MB < 4MB L2; v4 FETCH 12MB).
// 3-deep K/V pipeline with counted vmcnt kept. Job A->B transition race-free:
// job A's last iter ends vmcnt(0)+lgkmcnt(0)+barrier before job B restages.
__global__ __launch_bounds__(256, 2) void fattn_kernel(
    const _Float16* __restrict__ qh, const _Float16* __restrict__ kh,
    const _Float16* __restrict__ vth, _Float16* __restrict__ ah) {
  __shared__ __align__(16) _Float16 Kt[3][4096];
  __shared__ __align__(16) _Float16 Vt[3][4096];
  __shared__ __align__(16) _Float16 Pb[4][16][72];
  const int lin  = (int)blockIdx.x;          // 0..255
  const int xcd  = lin & 7;
  const int slot = lin >> 3;                 // 0..31 within XCD
  const int bh   = xcd * 4 + (slot & 3);     // 4 bh per XCD
  const int pair = slot >> 2;                // 0..7
  const int t = threadIdx.x;
  const int wv = t >> 6, lane = t & 63, l16 = lane & 15, quad = lane >> 4;
  const int b = bh >> 4, h = bh & 15;
  const _Float16* kg = kh + (size_t)bh * NN * DHH;
  const _Float16* vg = vth + (size_t)bh * DHH * NN;
  half8 ones;
#pragma unroll
  for (int j = 0; j < 8; ++j) ones[j] = (_Float16)1.f;

#define STAGE_KV(tile, nb) do {                                                \
    const _Float16* kn_ = kg + (size_t)(tile) * 64 * DHH;                      \
    const _Float16* vn_ = vg + (tile) * 64;                                    \
    _Float16* kl_ = &Kt[nb][0];                                                \
    _Float16* vl_ = &Vt[nb][0];                                                \
    _Pragma("unroll")                                                          \
    for (int iss = 0; iss < 2; ++iss) {                                        \
      int cid = iss * 256 + wv * 64 + lane;                                    \
      int row = cid >> 3;                                                      \
      int c = (cid & 7) ^ (row & 7);                                           \
      GLD16(kn_ + (size_t)row * DHH + c * 8, kl_ + (iss * 256 + wv * 64) * 8); \
      GLD16(vn_ + (size_t)row * NN + c * 8, vl_ + (iss * 256 + wv * 64) * 8);  \
    }                                                                          \
  } while (0)

  for (int job = 0; job < 2; ++job) {
    const int qb = (job == 0) ? (15 - pair) : pair;
    const int q0 = qb * 128;
    half8 qf[2][2];
#pragma unroll
    for (int qt2 = 0; qt2 < 2; ++qt2) {
      const _Float16* qp =
          qh + ((size_t)bh * NN + q0 + wv * 32 + qt2 * 16 + l16) * DHH + quad * 8;
      qf[qt2][0] = *(const half8*)qp;
      qf[qt2][1] = *(const half8*)(qp + 32);
    }
    f32x4 o[2][4] = {};
    f32x4 ls[2] = {};
    const int ktmax = 2 * qb + 1;   // >= 1 always
    // prologue: tiles 0 and 1 (ktmax >= 1 so both exist)
    STAGE_KV(0, 0);
    STAGE_KV(1, 1);
    int cur = 0;
    for (int kt = 0; kt <= ktmax; ++kt) {
      if (kt + 2 <= ktmax) {
        int nb = cur + 2; if (nb >= 3) nb -= 3;
        STAGE_KV(kt + 2, nb);
        asm volatile("s_waitcnt vmcnt(8)" ::: "memory");  // tile kt landed
      } else if (kt + 1 <= ktmax) {
        asm volatile("s_waitcnt vmcnt(4)" ::: "memory");
      } else {
        asm volatile("s_waitcnt vmcnt(0)" ::: "memory");
      }
      __builtin_amdgcn_s_barrier();
      asm volatile("" ::: "memory");
      if (kt * 64 <= q0 + wv * 32 + 31) {
        half8 kf[4][2], vf[4][2];
        const _Float16* Kb = &Kt[cur][0];
        const _Float16* Vb = &Vt[cur][0];
#pragma unroll
        for (int nt = 0; nt < 4; ++nt) {
          int row = nt * 16 + l16;
          int r7 = row & 7;
          kf[nt][0] = *(const half8*)(Kb + row * 64 + ((quad ^ r7) * 8));
          kf[nt][1] = *(const half8*)(Kb + row * 64 + (((quad + 4) ^ r7) * 8));
          vf[nt][0] = *(const half8*)(Vb + row * 64 + ((quad ^ r7) * 8));
          vf[nt][1] = *(const half8*)(Vb + row * 64 + (((quad + 4) ^ r7) * 8));
        }
#pragma unroll
        for (int qt2 = 0; qt2 < 2; ++qt2) {
          int base = q0 + wv * 32 + qt2 * 16;
          if (kt * 64 <= base + 15) {
            f32x4 s4[4];
#pragma unroll
            for (int nt = 0; nt < 4; ++nt) {
              f32x4 z = {};
              z = __builtin_amdgcn_mfma_f32_16x16x32_f16(qf[qt2][0], kf[nt][0], z, 0, 0, 0);
              s4[nt] = __builtin_amdgcn_mfma_f32_16x16x32_f16(qf[qt2][1], kf[nt][1], z, 0, 0, 0);
            }
            if (kt * 64 + 63 > base) {
#pragma unroll
              for (int nt = 0; nt < 4; ++nt) {
                int key = kt * 64 + nt * 16 + l16;
#pragma unroll
                for (int r = 0; r < 4; ++r) {
                  float p = (key > base + quad * 4 + r) ? 0.f : __expf(s4[nt][r]);
                  Pb[wv][quad * 4 + r][nt * 16 + l16] = (_Float16)p;
                }
              }
            } else {
#pragma unroll
              for (int nt = 0; nt < 4; ++nt)
#pragma unroll
                for (int r = 0; r < 4; ++r)
                  Pb[wv][quad * 4 + r][nt * 16 + l16] = (_Float16)__expf(s4[nt][r]);
            }
            asm volatile("s_waitcnt lgkmcnt(0)" ::: "memory");
            half8 pf0 = *(const half8*)&Pb[wv][l16][quad * 8];
            half8 pf1 = *(const half8*)&Pb[wv][l16][32 + quad * 8];
#pragma unroll
            for (int nt = 0; nt < 4; ++nt) {
              o[qt2][nt] = __builtin_amdgcn_mfma_f32_16x16x32_f16(pf0, vf[nt][0], o[qt2][nt], 0, 0, 0);
              o[qt2][nt] = __builtin_amdgcn_mfma_f32_16x16x32_f16(pf1, vf[nt][1], o[qt2][nt], 0, 0, 0);
            }
            ls[qt2] = __builtin_amdgcn_mfma_f32_16x16x32_f16(pf0, ones, ls[qt2], 0, 0, 0);
            ls[qt2] = __builtin_amdgcn_mfma_f32_16x16x32_f16(pf1, ones, ls[qt2], 0, 0, 0);
          }
        }
      }
      // all LDS reads of buf[cur] must RETIRE before any wave crosses this
      // barrier: iter kt+1's stage writes tile kt+3 into this same buffer.
      asm volatile("s_waitcnt lgkmcnt(0)" ::: "memory");
      __builtin_amdgcn_s_barrier();
      asm volatile("" ::: "memory");
      cur = (cur == 2) ? 0 : cur + 1;
    }
    // writeout for this job
#pragma unroll
    for (int qt2 = 0; qt2 < 2; ++qt2)
#pragma unroll
      for (int r = 0; r < 4; ++r) {
        float inv = 1.f / ls[qt2][r];
        int pos = q0 + wv * 32 + qt2 * 16 + quad * 4 + r;
        size_t ob = ((size_t)(b * NN + pos)) * DIMM + h * DHH;
#pragma unroll
        for (int nt = 0; nt < 4; ++nt)
          ah[ob + nt * 16 + l16] = (_Float16)(o[qt2][nt][r] * inv);
      }
  }
#undef STAGE_KV
}

// ---------------- out GEMM: 64x64 tile, BK=64, dbuf + counted vmcnt + bias ----------------
__global__ __launch_bounds__(256) void gemm_out_kernel(
    const _Float16* __restrict__ ah, const _Float16* __restrict__ wot,
    const float* __restrict__ bo, float* __restrict__ out) {
  __shared__ __align__(16) char smem[32768];
  _Float16* As = (_Float16*)smem;
  _Float16* Bs = (_Float16*)(smem + 16384);
  const int m0 = blockIdx.x * 64;
  const int n0 = blockIdx.y * 64;
  const int t = threadIdx.x;
  const int wv = t >> 6, lane = t & 63, l16 = lane & 15, quad = lane >> 4;
  const int r  = t >> 3;
  const int cl = t & 7;
  const int csw = (cl ^ (r & 7)) * 8;
  const _Float16* pa0 = ah + (size_t)(m0 + r) * 1024 + csw;
  const _Float16* pa1 = pa0 + 32 * 1024;
  const _Float16* pb0 = wot + (size_t)(n0 + r) * 1024 + csw;
  const _Float16* pb1 = pb0 + 32 * 1024;
  f32x4 acc[4] = {};
  const int arow = wv * 16 + l16;
  const int a7 = arow & 7;
  GLD16(pa0, As + wv * 512);
  GLD16(pa1, As + 2048 + wv * 512);
  GLD16(pb0, Bs + wv * 512);
  GLD16(pb1, Bs + 2048 + wv * 512);
  int cur = 0;
  for (int k0 = 0; k0 < 1024; k0 += 64) {
    if (k0 + 64 < 1024) {
      const int nb = cur ^ 1;
      GLD16(pa0 + k0 + 64, As + nb * 4096 + wv * 512);
      GLD16(pa1 + k0 + 64, As + nb * 4096 + 2048 + wv * 512);
      GLD16(pb0 + k0 + 64, Bs + nb * 4096 + wv * 512);
      GLD16(pb1 + k0 + 64, Bs + nb * 4096 + 2048 + wv * 512);
      asm volatile("s_waitcnt vmcnt(4)" ::: "memory");
    } else {
      asm volatile("s_waitcnt vmcnt(0)" ::: "memory");
    }
    __builtin_amdgcn_s_barrier();
    asm volatile("" ::: "memory");
    const _Float16* Ab = As + cur * 4096;
    const _Float16* Bb = Bs + cur * 4096;
    half8 af0 = *(const half8*)(Ab + arow * 64 + (quad ^ a7) * 8);
    half8 af1 = *(const half8*)(Ab + arow * 64 + ((4 + quad) ^ a7) * 8);
#pragma unroll
    for (int nt = 0; nt < 4; ++nt) {
      int brow = nt * 16 + l16;
      int b7 = brow & 7;
      half8 bf0 = *(const half8*)(Bb + brow * 64 + (quad ^ b7) * 8);
      half8 bf1 = *(const half8*)(Bb + brow * 64 + ((4 + quad) ^ b7) * 8);
      acc[nt] = __builtin_amdgcn_mfma_f32_16x16x32_f16(af0, bf0, acc[nt], 0, 0, 0);
      acc[nt] = __builtin_amdgcn_mfma_f32_16x16x32_f16(af1, bf1, acc[nt], 0, 0, 0);
    }
    asm volatile("s_waitcnt lgkmcnt(0)" ::: "memory");
    __builtin_amdgcn_s_barrier();
    asm volatile("" ::: "memory");
    cur ^= 1;
  }
#pragma unroll
  for (int nt = 0; nt < 4; ++nt) {
    int col = n0 + nt * 16 + l16;
    float bias = bo[col];
#pragma unroll
    for (int rr = 0; rr < 4; ++rr) {
      out[(size_t)(m0 + wv * 16 + quad * 4 + rr) * 1024 + col] = acc[nt][rr] + bias;
    }
  }
}

extern "C" void kernel_launch(void* const* d_in, const int* in_sizes, int n_in,
                              void* d_out, int out_size, void* d_ws, size_t ws_size,
                              hipStream_t stream) {
  (void)in_sizes; (void)n_in; (void)out_size; (void)ws_size;
  const float* x  = (const float*)d_in[0];
  const float* Wq = (const float*)d_in[1];
  const float* Wk = (const float*)d_in[2];
  const float* Wv = (const float*)d_in[3];
  const float* Wo = (const float*)d_in[4];
  const float* bo = (const float*)d_in[5];

  float* out = (float*)d_out;
  float* ko  = out + (size_t)MMR * DIMM;
  float* vo  = ko + (size_t)BB * NHH * NN * DHH;

  char* w = (char*)d_ws;
  _Float16* xh  = (_Float16*)w;                   // 8 MB (dead after gemm_qkv)
  _Float16* ah  = (_Float16*)w;                   // 8 MB (reuses xh region)
  _Float16* wt  = (_Float16*)(w + (8u << 20));    // 8 MB
  _Float16* qh  = (_Float16*)(w + (16u << 20));   // 8 MB (b,h,n,dh) roped, *0.125
  _Float16* kh  = (_Float16*)(w + (24u << 20));   // 8 MB (b,h,n,dh) roped
  _Float16* vth = (_Float16*)(w + (32u << 20));   // 8 MB (b,h,dh,n)

  hipLaunchKernelGGL(cvt_x_kernel, dim3(4096), dim3(256), 0, stream, x, xh);
  hipLaunchKernelGGL(transpose_w_kernel, dim3(16, 16, 4), dim3(256), 0, stream,
                     Wq, Wk, Wv, Wo, wt);
  hipLaunchKernelGGL(gemm_qkv_kernel, dim3(64, 48), dim3(256), 0, stream,
                     xh, wt, ko, vo, qh, kh, vth);
  hipLaunchKernelGGL(fattn_kernel, dim3(256), dim3(256), 0, stream,
                     qh, kh, vth, ah);
  hipLaunchKernelGGL(gemm_out_kernel, dim3(64, 16), dim3(256), 0, stream,
                     ah, wt + (size_t)3 * 1024 * 1024, bo, out);
}